// Round 9
// baseline (165.542 us; speedup 1.0000x reference)
//
#include <hip/hip_runtime.h>
#include <math.h>

#define J 25
#define NJC 75             // J * CIN
#define NWAVE 4            // waves per block
#define NTHREADS 256
#define NFPW 8             // frames per wave
#define SCRW 1056          // per-wave scratch: 4 blocks x 264 bf16 (X staging only)

// const-image layout (bf16 element offsets in ws)
#define O_A1T  0           // B-frag [k=j][n=i], 1024
#define O_APP  1024        // frag [i'][j] (serves as B [k=j][n=i']), 1024
#define O_A4B  2048        // A-frag [m=i''][k=j], 1024
#define O_W2T  3072        // frag [l][d] (serves as B [k=d][n=l]), 2048
#define O_W3T  5120        // A-frag [m=d][k=l], 2 M-tiles, 2048
#define O_W1T  7168        // padded [tt][half][m][c8], half1=0, 1024
#define O_W4C  8192        // [n=c][k=d], 256
#define O_BPPB 8448        // 64 bf16 packed in C-reg order per (tt,half)
#define O_B4   8512        // 4 floats

using bf16x4 = __attribute__((ext_vector_type(4))) __bf16;
using bf16x8 = __attribute__((ext_vector_type(8))) __bf16;
using f32x16 = __attribute__((ext_vector_type(16))) float;

__device__ inline bf16x8 zero8() {
    bf16x8 z;
    #pragma unroll
    for (int j = 0; j < 8; j++) z[j] = (__bf16)0.f;
    return z;
}

__device__ inline unsigned pkbf(float a, float b) {
    union { __bf16 h; unsigned short u; } ua, ub;
    ua.h = (__bf16)a; ub.h = (__bf16)b;
    return (unsigned)ua.u | ((unsigned)ub.u << 16);
}

// ---------------------------------------------------------------------------
// C-layout (f32x16) -> two bf16x8 operand frags (k = C-row dim, lane preserved)
// via a single half0<->half1 exchange of 4 dwords (lx = lane ^ 32).
// Row groups: pair p_i = rows (2i,2i+1) of this half's ladder:
//   p0,p1 = rows{0-3}+4h; p2,p3 = rows{8-11}+4h; p4,p5 = {16-19}+4h; p6,p7 = {24-27}+4h
// half0 keeps p0,p1 (k0-3) & p4,p5 (k16-19), sends p2,p3 & p6,p7;
// half1 keeps p2,p3 (k12-15) & p6,p7 (k28-31), sends p0,p1 & p4,p5.
//   f0 = half0 ? [p0,p1,r0,r1] : [r0,r1,p2,p3]   (k 0-15 across halves)
//   f1 = half0 ? [p4,p5,r2,r3] : [r2,r3,p6,p7]   (k 16-31)
// ---------------------------------------------------------------------------
__device__ inline void cswap(const f32x16 acc, int half, int lx,
                             bf16x8* f0, bf16x8* f1) {
    const unsigned p0 = pkbf(acc[0],  acc[1]),  p1 = pkbf(acc[2],  acc[3]);
    const unsigned p2 = pkbf(acc[4],  acc[5]),  p3 = pkbf(acc[6],  acc[7]);
    const unsigned p4 = pkbf(acc[8],  acc[9]),  p5 = pkbf(acc[10], acc[11]);
    const unsigned p6 = pkbf(acc[12], acc[13]), p7 = pkbf(acc[14], acc[15]);
    const unsigned s0 = half ? p0 : p2, s1 = half ? p1 : p3;
    const unsigned s2 = half ? p4 : p6, s3 = half ? p5 : p7;
    const unsigned r0 = (unsigned)__shfl((int)s0, lx, 64);
    const unsigned r1 = (unsigned)__shfl((int)s1, lx, 64);
    const unsigned r2 = (unsigned)__shfl((int)s2, lx, 64);
    const unsigned r3 = (unsigned)__shfl((int)s3, lx, 64);
    uint4 u0, u1;
    u0.x = half ? r0 : p0;  u0.y = half ? r1 : p1;
    u0.z = half ? p2 : r0;  u0.w = half ? p3 : r1;
    u1.x = half ? r2 : p4;  u1.y = half ? r3 : p5;
    u1.z = half ? p6 : r2;  u1.w = half ? p7 : r3;
    *f0 = *(bf16x8*)&u0;  *f1 = *(bf16x8*)&u1;
}

// ---------------------------------------------------------------------------
// Precompute (1 block, 256 thr): softmax(A1..A4), App=A3s@A2s, bpp=W3^T b2+b3,
// then emit the complete bf16 frag-layout constant image to ws.
// ---------------------------------------------------------------------------
__global__ void gcn_precompute(
    const float* __restrict__ A1, const float* __restrict__ W1, const float* __restrict__ b1,
    const float* __restrict__ A2, const float* __restrict__ W2, const float* __restrict__ b2,
    const float* __restrict__ A3, const float* __restrict__ W3, const float* __restrict__ b3,
    const float* __restrict__ A4, const float* __restrict__ W4, const float* __restrict__ b4,
    __bf16* __restrict__ cw)
{
    __shared__ float T[3125];      // T0..T3 softmax(A1..A4), T4 = App
    __shared__ float bpp[64];
    float* T0 = T;        float* T1 = T + 625;  float* T2 = T + 1250;
    float* T3 = T + 1875; float* T4 = T + 2500;
    const int t = threadIdx.x;

    if (t < 100) {
        const int m = t / J, i = t % J;
        const float* Asrc = (m == 0) ? A1 : (m == 1) ? A2 : (m == 2) ? A3 : A4;
        float row[J];
        float mx = -1e30f;
        #pragma unroll
        for (int j = 0; j < J; j++) { row[j] = Asrc[i * J + j]; mx = fmaxf(mx, row[j]); }
        float s = 0.f;
        #pragma unroll
        for (int j = 0; j < J; j++) { row[j] = __expf(row[j] - mx); s += row[j]; }
        const float inv = 1.f / s;
        float* dst = T + m * 625 + i * J;
        #pragma unroll
        for (int j = 0; j < J; j++) dst[j] = row[j] * inv;
    }
    if (t < 64) {                                      // bpp = W3^T b2 + b3
        float s = b3[t];
        #pragma unroll
        for (int l = 0; l < 32; l++) s += W3[l * 64 + t] * b2[l];
        bpp[t] = s;
    }
    __syncthreads();

    for (int idx = t; idx < 625; idx += 256) {        // App = A3s @ A2s
        const int i = idx / J, jj = idx % J;
        float s = 0.f;
        #pragma unroll
        for (int k = 0; k < J; k++) s += T2[i * J + k] * T1[k * J + jj];
        T4[idx] = s;
    }
    __syncthreads();

    // ---- frag-layout tables (mappings R4..R8-verified) ----
    for (int i = t; i < 1024; i += 256) {
        const int b = i >> 8, n = (i >> 3) & 31, jj = i & 7, j = 8 * b + jj;
        const bool ok = (j < J) && (n < J);
        cw[O_A1T + i] = (__bf16)(ok ? T0[n * J + j] : 0.f);
        cw[O_APP + i] = (__bf16)(ok ? T4[n * J + j] : 0.f);
        cw[O_A4B + i] = (__bf16)(ok ? T3[n * J + j] : 0.f);
    }
    for (int i = t; i < 2048; i += 256) {
        const int b = i >> 8, m = (i >> 3) & 31, jj = i & 7;
        cw[O_W2T + i] = (__bf16)W2[(8 * b + jj) * 32 + m];             // [l][d]
        const int tt = i >> 10, r = i & 1023;
        const int b3i = r >> 8, m3 = (r >> 3) & 31, j3 = r & 7;
        cw[O_W3T + i] = (__bf16)W3[(8 * b3i + j3) * 64 + tt * 32 + m3]; // [m=d][k=l]
    }
    for (int i = t; i < 1024; i += 256) {             // W1T padded, half1 = 0
        const int tt = i >> 9, r = i & 511, hf = r >> 8, q = r & 255;
        const int m = q >> 3, c = q & 7, d = tt * 32 + m;
        float v = 0.f;
        if (hf == 0) {
            if (c < 3) v = W1[c * 64 + d];
            else if (c == 3) v = b1[d];
        }
        cw[O_W1T + i] = (__bf16)v;
    }
    if (t < 256)
        cw[O_W4C + t] = (t < 192) ? (__bf16)W4[(t & 63) * 3 + (t >> 6)] : (__bf16)0.f;

    if (t < 64) {                                      // packed bias, C-reg order
        const int tt = t >> 5, rem = t & 31, hf = rem >> 4, q = rem & 15;
        const int g = q >> 2, r2 = q & 3;
        cw[O_BPPB + t] = (__bf16)bpp[tt * 32 + 8 * g + 4 * hf + r2];
    }
    float* fb4 = (float*)(cw + O_B4);
    if (t >= 64 && t < 68) fb4[t - 64] = (t < 67) ? b4[t - 64] : 0.f;
}

// ---------------------------------------------------------------------------
// Fused kernel. One wave per NFPW=8 frames; weights register-resident.
// ALL inter-stage transforms are in-register half-swaps (cswap) — LDS is used
// ONLY for X staging (scatter -> A-frag). Zero barriers (per-wave in-order).
//
// mfma_f32_32x32x16_bf16 (verified): A[m][k]: m=lane&31, k=8*(lane>>5)+j+16ks
//   B[k][n]: n=lane&31, same k.  C/D: col=lane&31, row=(reg&3)+8*(reg>>2)+4*(lane>>5)
//
// Chain (lane-preserving at every step):
//   P1: Y^T = Xaug^T @ A1T          C cols=i     (rows c -> in-reg yb)
//   P2: H^T = relu(W1 @ Y^T)        C cols=i, rows=d   -> cswap -> hf[4]
//   P3: U   = H @ W2                C cols=l, rows=i   -> cswap -> uf[2]
//   P4: V^T = U^T @ App^T           C cols=i', rows=l  -> cswap -> vf[2]
//   P5: HD^T= relu(W3 @ V^T + bpp)  C cols=i', rows=d  -> cswap -> hd[4]
//   P6: P   = HD @ W4               C cols=c,  rows=i' -> cswap -> pf[2]
//   P7: out = A4 @ P + b4           C cols=c,  rows=i''-> global stores
// ---------------------------------------------------------------------------
__global__ __launch_bounds__(NTHREADS, 3) void gcn_fused(
    const float* __restrict__ x,
    const __bf16* __restrict__ cw,
    float* __restrict__ out)
{
    __shared__ __align__(16) __bf16 SCR[NWAVE * SCRW];

    const int t = threadIdx.x;
    const int w = t >> 6, lane = t & 63, ln = lane & 31, half = lane >> 5;
    const int lx = lane ^ 32;
    const int fo = ln * 8;
    __bf16* sc = &SCR[w * SCRW];

    const long fbase = ((long)blockIdx.x * NWAVE + w) * NFPW;

    // ---- first-frame x prefetch
    long xb = fbase * NJC;
    float xv0 = x[xb + lane];
    float xv1 = (lane < NJC - 64) ? x[xb + 64 + lane] : 0.f;

    // ---- register frag loads (once per wave, from global ws image)
    bf16x8 rA1T[2], rApp[2], rA4b[2], rW1[2], rW2[4], rW3[4], rW4[4], rBpp[4];
    #pragma unroll
    for (int ks = 0; ks < 2; ks++) {
        rA1T[ks] = *(const bf16x8*)&cw[O_A1T + (2 * ks + half) * 256 + fo];
        rApp[ks] = *(const bf16x8*)&cw[O_APP + (2 * ks + half) * 256 + fo];
        rA4b[ks] = *(const bf16x8*)&cw[O_A4B + (2 * ks + half) * 256 + fo];
        rW1[ks]  = *(const bf16x8*)&cw[O_W1T + ks * 512 + half * 256 + fo];
    }
    #pragma unroll
    for (int ks = 0; ks < 4; ks++)
        rW2[ks] = *(const bf16x8*)&cw[O_W2T + (half + 2 * ks) * 256 + fo];
    #pragma unroll
    for (int tt = 0; tt < 2; tt++)
        #pragma unroll
        for (int ks = 0; ks < 2; ks++)
            rW3[tt * 2 + ks] = *(const bf16x8*)&cw[O_W3T + tt * 1024 + (half + 2 * ks) * 256 + fo];
    #pragma unroll
    for (int ks = 0; ks < 4; ks++) {
        rW4[ks] = zero8();
        if (ln < 3) rW4[ks] = *(const bf16x8*)&cw[O_W4C + ln * 64 + (half + 2 * ks) * 8];
    }
    #pragma unroll
    for (int tt = 0; tt < 2; tt++)
        #pragma unroll
        for (int p = 0; p < 2; p++)
            rBpp[tt * 2 + p] = *(const bf16x8*)&cw[O_BPPB + (tt * 2 + half) * 16 + p * 8];
    float b4v = 0.f;
    if (ln < 3) b4v = ((const float*)(cw + O_B4))[ln];

    // ---- shared zero accumulator (MFMA allows D != C)
    f32x16 Z;
    #pragma unroll
    for (int z = 0; z < 16; z++) Z[z] = 0.f;

    for (int fi = 0; fi < NFPW; fi++) {
        const long f = fbase + fi;

        // ---- X staging (LDS): A-frag rows 0-2 = channels, row 3 = ones
        {
            const int i0 = lane, c0 = i0 % 3, j0 = i0 / 3;
            sc[(j0 >> 3) * 264 + c0 * 8 + (j0 & 7)] = (__bf16)xv0;
            if (lane < NJC - 64) {
                const int i1 = 64 + lane, c1 = i1 % 3, j1 = i1 / 3;
                sc[(j1 >> 3) * 264 + c1 * 8 + (j1 & 7)] = (__bf16)xv1;
            }
            if (half == 0) sc[(ln >> 3) * 264 + 24 + (ln & 7)] = (ln < J) ? (__bf16)1.f : (__bf16)0.f;
            if (lane < 21) sc[3 * 264 + (lane / 7) * 8 + 1 + (lane % 7)] = (__bf16)0.f;
        }

        // ---- prefetch next frame's x
        float nxv0 = 0.f, nxv1 = 0.f;
        if (fi + 1 < NFPW) {
            const long nxb = (f + 1) * NJC;
            nxv0 = x[nxb + lane];
            if (lane < NJC - 64) nxv1 = x[nxb + 64 + lane];
        }

        // ---- P1: Y^T = Xaug^T @ A1T
        f32x16 accY;
        {
            bf16x8 a0 = *(const bf16x8*)&sc[half * 264 + fo];
            accY = __builtin_amdgcn_mfma_f32_32x32x16_bf16(a0, rA1T[0], Z, 0, 0, 0);
            bf16x8 a1 = *(const bf16x8*)&sc[(2 + half) * 264 + fo];
            accY = __builtin_amdgcn_mfma_f32_32x32x16_bf16(a1, rA1T[1], accY, 0, 0, 0);
        }

        // ---- P2: H^T = relu(W1 @ Y^T); Y consumed in-register
        bf16x8 yb;
        #pragma unroll
        for (int jj = 0; jj < 8; jj++)
            yb[jj] = (half == 0 && jj < 4) ? (__bf16)accY[jj] : (__bf16)0.f;
        bf16x8 hf[4];
        #pragma unroll
        for (int tt = 0; tt < 2; tt++) {
            f32x16 acc = __builtin_amdgcn_mfma_f32_32x32x16_bf16(rW1[tt], yb, Z, 0, 0, 0);
            #pragma unroll
            for (int z = 0; z < 16; z++) acc[z] = fmaxf(acc[z], 0.f);
            cswap(acc, half, lx, &hf[tt * 2], &hf[tt * 2 + 1]);
        }

        // ---- P3: U = H @ W2  (C cols = l, rows = i)
        f32x16 accU = __builtin_amdgcn_mfma_f32_32x32x16_bf16(hf[0], rW2[0], Z, 0, 0, 0);
        #pragma unroll
        for (int ks = 1; ks < 4; ks++)
            accU = __builtin_amdgcn_mfma_f32_32x32x16_bf16(hf[ks], rW2[ks], accU, 0, 0, 0);
        bf16x8 uf[2];
        cswap(accU, half, lx, &uf[0], &uf[1]);

        // ---- P4: V^T = U^T @ App^T  (C cols = i', rows = l)
        f32x16 accV = __builtin_amdgcn_mfma_f32_32x32x16_bf16(uf[0], rApp[0], Z, 0, 0, 0);
        accV = __builtin_amdgcn_mfma_f32_32x32x16_bf16(uf[1], rApp[1], accV, 0, 0, 0);
        bf16x8 vf[2];
        cswap(accV, half, lx, &vf[0], &vf[1]);

        // ---- P5: HD^T = relu(W3 @ V^T + bpp)  (C cols = i', rows = d)
        bf16x8 hd[4];
        #pragma unroll
        for (int tt = 0; tt < 2; tt++) {
            f32x16 acc = __builtin_amdgcn_mfma_f32_32x32x16_bf16(rW3[tt * 2 + 0], vf[0], Z, 0, 0, 0);
            acc = __builtin_amdgcn_mfma_f32_32x32x16_bf16(rW3[tt * 2 + 1], vf[1], acc, 0, 0, 0);
            #pragma unroll
            for (int q = 0; q < 16; q++) {
                const float bias = (float)rBpp[tt * 2 + (q >> 3)][q & 7];
                acc[q] = fmaxf(acc[q] + bias, 0.f);
            }
            cswap(acc, half, lx, &hd[tt * 2], &hd[tt * 2 + 1]);
        }

        // ---- P6: P = HD @ W4  (C cols = c, rows = i')
        f32x16 accP = __builtin_amdgcn_mfma_f32_32x32x16_bf16(hd[0], rW4[0], Z, 0, 0, 0);
        #pragma unroll
        for (int ks = 1; ks < 4; ks++)
            accP = __builtin_amdgcn_mfma_f32_32x32x16_bf16(hd[ks], rW4[ks], accP, 0, 0, 0);
        bf16x8 pf[2];
        cswap(accP, half, lx, &pf[0], &pf[1]);

        // ---- P7: out = A4 @ P + b4, direct global stores
        f32x16 accO = __builtin_amdgcn_mfma_f32_32x32x16_bf16(rA4b[0], pf[0], Z, 0, 0, 0);
        accO = __builtin_amdgcn_mfma_f32_32x32x16_bf16(rA4b[1], pf[1], accO, 0, 0, 0);
        if (ln < 3) {
            const long ob = f * NJC;
            #pragma unroll
            for (int r = 0; r < 16; r++) {
                const int row = (r & 3) + 8 * (r >> 2) + 4 * half;
                if (row < J) out[ob + row * 3 + ln] = accO[r] + b4v;
            }
        }

        xv0 = nxv0; xv1 = nxv1;
    }
}

// ---------------------------------------------------------------------------
extern "C" void kernel_launch(void* const* d_in, const int* in_sizes, int n_in,
                              void* d_out, int out_size, void* d_ws, size_t ws_size,
                              hipStream_t stream)
{
    const float* x  = (const float*)d_in[0];
    const float* A1 = (const float*)d_in[1];
    const float* W1 = (const float*)d_in[2];
    const float* b1 = (const float*)d_in[3];
    const float* A2 = (const float*)d_in[4];
    const float* W2 = (const float*)d_in[5];
    const float* b2 = (const float*)d_in[6];
    const float* A3 = (const float*)d_in[7];
    const float* W3 = (const float*)d_in[8];
    const float* b3 = (const float*)d_in[9];
    const float* A4 = (const float*)d_in[10];
    const float* W4 = (const float*)d_in[11];
    const float* b4 = (const float*)d_in[12];
    float* out = (float*)d_out;
    __bf16* cw = (__bf16*)d_ws;

    const int NT = in_sizes[0] / NJC;                 // 65536
    const int nblocks = NT / (NWAVE * NFPW);          // 2048

    gcn_precompute<<<1, 256, 0, stream>>>(
        A1, W1, b1, A2, W2, b2, A3, W3, b3, A4, W4, b4, cw);
    gcn_fused<<<nblocks, NTHREADS, 0, stream>>>(x, cw, out);
}

// Round 11
// 155.718 us; speedup vs baseline: 1.0631x; 1.0631x over previous
//
#include <hip/hip_runtime.h>
#include <math.h>

#define J 25
#define NJC 75             // J * CIN
#define NWAVE 4            // waves per block
#define NTHREADS 256
#define NFPW 8             // frames per wave (processed 2 at a time)
#define SCRW 4224          // per-wave scratch: 2 frames x 8 blocks x 264 bf16

// const-image layout (bf16 element offsets in ws)
#define O_A1T  0           // B-frag [k=j][n=i], 1024
#define O_APP  1024        // frag [i'][j] (serves as B [k=j][n=i']), 1024
#define O_A4B  2048        // A-frag [m=i''][k=j], 1024
#define O_W2T  3072        // frag [l][d] (serves as B [k=d][n=l]), 2048
#define O_W3T  5120        // A-frag [m=d][k=l], 2 M-tiles, 2048
#define O_W1T  7168        // padded [tt][half][m][c8], half1=0, 1024
#define O_W4C  8192        // [n=c][k=d], 256
#define O_BPPB 8448        // 64 bf16 packed in C-reg order per (tt,half)
#define O_B4   8512        // 4 floats

using bf16x4 = __attribute__((ext_vector_type(4))) __bf16;
using bf16x8 = __attribute__((ext_vector_type(8))) __bf16;
using f32x16 = __attribute__((ext_vector_type(16))) float;

__device__ inline bf16x8 zero8() {
    bf16x8 z;
    #pragma unroll
    for (int j = 0; j < 8; j++) z[j] = (__bf16)0.f;
    return z;
}

// ---------------------------------------------------------------------------
// Precompute (1 block, 256 thr): softmax(A1..A4), App=A3s@A2s, bpp=W3^T b2+b3,
// then emit the complete bf16 frag-layout constant image to ws.
// ---------------------------------------------------------------------------
__global__ void gcn_precompute(
    const float* __restrict__ A1, const float* __restrict__ W1, const float* __restrict__ b1,
    const float* __restrict__ A2, const float* __restrict__ W2, const float* __restrict__ b2,
    const float* __restrict__ A3, const float* __restrict__ W3, const float* __restrict__ b3,
    const float* __restrict__ A4, const float* __restrict__ W4, const float* __restrict__ b4,
    __bf16* __restrict__ cw)
{
    __shared__ float T[3125];      // T0..T3 softmax(A1..A4), T4 = App
    __shared__ float bpp[64];
    float* T0 = T;        float* T1 = T + 625;  float* T2 = T + 1250;
    float* T3 = T + 1875; float* T4 = T + 2500;
    const int t = threadIdx.x;

    if (t < 100) {
        const int m = t / J, i = t % J;
        const float* Asrc = (m == 0) ? A1 : (m == 1) ? A2 : (m == 2) ? A3 : A4;
        float row[J];
        float mx = -1e30f;
        #pragma unroll
        for (int j = 0; j < J; j++) { row[j] = Asrc[i * J + j]; mx = fmaxf(mx, row[j]); }
        float s = 0.f;
        #pragma unroll
        for (int j = 0; j < J; j++) { row[j] = __expf(row[j] - mx); s += row[j]; }
        const float inv = 1.f / s;
        float* dst = T + m * 625 + i * J;
        #pragma unroll
        for (int j = 0; j < J; j++) dst[j] = row[j] * inv;
    }
    if (t < 64) {                                      // bpp = W3^T b2 + b3
        float s = b3[t];
        #pragma unroll
        for (int l = 0; l < 32; l++) s += W3[l * 64 + t] * b2[l];
        bpp[t] = s;
    }
    __syncthreads();

    for (int idx = t; idx < 625; idx += 256) {        // App = A3s @ A2s
        const int i = idx / J, jj = idx % J;
        float s = 0.f;
        #pragma unroll
        for (int k = 0; k < J; k++) s += T2[i * J + k] * T1[k * J + jj];
        T4[idx] = s;
    }
    __syncthreads();

    // ---- frag-layout tables (mappings R4..R8-verified) ----
    for (int i = t; i < 1024; i += 256) {
        const int b = i >> 8, n = (i >> 3) & 31, jj = i & 7, j = 8 * b + jj;
        const bool ok = (j < J) && (n < J);
        cw[O_A1T + i] = (__bf16)(ok ? T0[n * J + j] : 0.f);
        cw[O_APP + i] = (__bf16)(ok ? T4[n * J + j] : 0.f);
        cw[O_A4B + i] = (__bf16)(ok ? T3[n * J + j] : 0.f);
    }
    for (int i = t; i < 2048; i += 256) {
        const int b = i >> 8, m = (i >> 3) & 31, jj = i & 7;
        cw[O_W2T + i] = (__bf16)W2[(8 * b + jj) * 32 + m];             // [l][d]
        const int tt = i >> 10, r = i & 1023;
        const int b3i = r >> 8, m3 = (r >> 3) & 31, j3 = r & 7;
        cw[O_W3T + i] = (__bf16)W3[(8 * b3i + j3) * 64 + tt * 32 + m3]; // [m=d][k=l]
    }
    for (int i = t; i < 1024; i += 256) {             // W1T padded, half1 = 0
        const int tt = i >> 9, r = i & 511, hf = r >> 8, q = r & 255;
        const int m = q >> 3, c = q & 7, d = tt * 32 + m;
        float v = 0.f;
        if (hf == 0) {
            if (c < 3) v = W1[c * 64 + d];
            else if (c == 3) v = b1[d];
        }
        cw[O_W1T + i] = (__bf16)v;
    }
    if (t < 256)
        cw[O_W4C + t] = (t < 192) ? (__bf16)W4[(t & 63) * 3 + (t >> 6)] : (__bf16)0.f;

    if (t < 64) {                                      // packed bias, C-reg order
        const int tt = t >> 5, rem = t & 31, hf = rem >> 4, q = rem & 15;
        const int g = q >> 2, r2 = q & 3;
        cw[O_BPPB + t] = (__bf16)bpp[tt * 32 + 8 * g + 4 * hf + r2];
    }
    float* fb4 = (float*)(cw + O_B4);
    if (t >= 64 && t < 68) fb4[t - 64] = (t < 67) ? b4[t - 64] : 0.f;
}

// ---------------------------------------------------------------------------
// Fused kernel (R8 structure + 2-frame software pipelining).
// One wave processes NFPW=8 frames, TWO per iteration with fully interleaved
// stages (independent dependency chains -> latency hiding). Weights register-
// resident; LDS scratch = 2 regions x 8 blocks x 264 bf16 per wave; per-wave
// DS ops are in-order -> zero barriers (R3..R8-proven).
//
// NOTE (R10 post-mortem): the ones-row (bias slot, A-frag row m=3) is DATA and
// is overwritten by P2/P5/P6 each iteration -> must be rewritten per frame.
// The K-pad slots (k>=25 on A-side) need NO zeroing: the B-operand tables
// (A1T) have zero rows for k>=25 and all scratch junk is finite (0*junk=0).
//
// mfma_f32_32x32x16_bf16 (verified): A[m][k]: m=lane&31, k=8*(lane>>5)+j+16ks
//   B[k][n]: n=lane&31, same k.  C/D: col=lane&31, row=(reg&3)+8*(reg>>2)+4*(lane>>5)
//
// Per-region scratch schedule: X A-frag rows 0-3 (blks 0-3) -> P2 H (blks 0-7)
//   -> P3 U (blks 0-3) -> P4 V^T (blks 4-7) -> P5 HD (blks 0-7) -> P6 P (blks 0-3)
// ---------------------------------------------------------------------------
__global__ __launch_bounds__(NTHREADS, 2) void gcn_fused(
    const float* __restrict__ x,
    const __bf16* __restrict__ cw,
    float* __restrict__ out)
{
    __shared__ __align__(16) __bf16 SCR[NWAVE * SCRW];

    const int t = threadIdx.x;
    const int w = t >> 6, lane = t & 63, ln = lane & 31, half = lane >> 5;
    const int fo = ln * 8;
    __bf16* sa = &SCR[w * SCRW];          // frame-A region (blks 0-7)
    __bf16* sb = sa + 8 * 264;            // frame-B region (blks 8-15)

    const long fbase = ((long)blockIdx.x * NWAVE + w) * NFPW;

    // ---- first pair x prefetch
    long xb = fbase * NJC;
    float xa0 = x[xb + lane];
    float xa1 = (lane < NJC - 64) ? x[xb + 64 + lane] : 0.f;
    float xb0 = x[xb + NJC + lane];
    float xb1 = (lane < NJC - 64) ? x[xb + NJC + 64 + lane] : 0.f;

    // ---- register frag loads (once per wave, from global ws image)
    bf16x8 rA1T[2], rApp[2], rA4b[2], rW1[2], rW2[4], rW3[4], rW4[4], rBpp[4];
    #pragma unroll
    for (int ks = 0; ks < 2; ks++) {
        rA1T[ks] = *(const bf16x8*)&cw[O_A1T + (2 * ks + half) * 256 + fo];
        rApp[ks] = *(const bf16x8*)&cw[O_APP + (2 * ks + half) * 256 + fo];
        rA4b[ks] = *(const bf16x8*)&cw[O_A4B + (2 * ks + half) * 256 + fo];
        rW1[ks]  = *(const bf16x8*)&cw[O_W1T + ks * 512 + half * 256 + fo];
    }
    #pragma unroll
    for (int ks = 0; ks < 4; ks++)
        rW2[ks] = *(const bf16x8*)&cw[O_W2T + (half + 2 * ks) * 256 + fo];
    #pragma unroll
    for (int tt = 0; tt < 2; tt++)
        #pragma unroll
        for (int ks = 0; ks < 2; ks++)
            rW3[tt * 2 + ks] = *(const bf16x8*)&cw[O_W3T + tt * 1024 + (half + 2 * ks) * 256 + fo];
    #pragma unroll
    for (int ks = 0; ks < 4; ks++) {
        rW4[ks] = zero8();
        if (ln < 3) rW4[ks] = *(const bf16x8*)&cw[O_W4C + ln * 64 + (half + 2 * ks) * 8];
    }
    #pragma unroll
    for (int tt = 0; tt < 2; tt++)
        #pragma unroll
        for (int p = 0; p < 2; p++)
            rBpp[tt * 2 + p] = *(const bf16x8*)&cw[O_BPPB + (tt * 2 + half) * 16 + p * 8];
    float b4v = 0.f;
    if (ln < 3) b4v = ((const float*)(cw + O_B4))[ln];

    // ---- shared zero accumulator (MFMA allows D != C)
    f32x16 Z;
    #pragma unroll
    for (int z = 0; z < 16; z++) Z[z] = 0.f;

    // scatter coords (frame-independent)
    const int c0 = lane % 3, j0 = lane / 3;
    const int sc0 = (j0 >> 3) * 264 + c0 * 8 + (j0 & 7);
    const int i1 = 64 + lane, c1 = i1 % 3, j1 = i1 / 3;
    const int sc1 = (j1 >> 3) * 264 + c1 * 8 + (j1 & 7);
    // ones-row coords (row m=3 across blocks 0-3, k = ln; 0 for k>=25)
    const int so = (ln >> 3) * 264 + 24 + (ln & 7);
    const __bf16 ov = (ln < J) ? (__bf16)1.f : (__bf16)0.f;

    for (int fi = 0; fi < NFPW; fi += 2) {
        const long fA = fbase + fi, fB = fA + 1;

        // ---- X staging (both frames): channels rows 0-2 + ones row m=3
        sa[sc0] = (__bf16)xa0;
        sb[sc0] = (__bf16)xb0;
        if (lane < NJC - 64) { sa[sc1] = (__bf16)xa1; sb[sc1] = (__bf16)xb1; }
        if (half == 0) { sa[so] = ov; sb[so] = ov; }   // rewritten EVERY frame

        // ---- prefetch next pair's x
        float nxa0 = 0.f, nxa1 = 0.f, nxb0 = 0.f, nxb1 = 0.f;
        if (fi + 2 < NFPW) {
            const long nxb_ = (fA + 2) * NJC;
            nxa0 = x[nxb_ + lane];
            nxb0 = x[nxb_ + NJC + lane];
            if (lane < NJC - 64) {
                nxa1 = x[nxb_ + 64 + lane];
                nxb1 = x[nxb_ + NJC + 64 + lane];
            }
        }

        // ---- P1: Y^T = Xaug^T @ A1T   (both frames)
        f32x16 accYa, accYb;
        {
            bf16x8 a0 = *(const bf16x8*)&sa[half * 264 + fo];
            bf16x8 b0 = *(const bf16x8*)&sb[half * 264 + fo];
            accYa = __builtin_amdgcn_mfma_f32_32x32x16_bf16(a0, rA1T[0], Z, 0, 0, 0);
            accYb = __builtin_amdgcn_mfma_f32_32x32x16_bf16(b0, rA1T[0], Z, 0, 0, 0);
            bf16x8 a1 = *(const bf16x8*)&sa[(2 + half) * 264 + fo];
            bf16x8 b1 = *(const bf16x8*)&sb[(2 + half) * 264 + fo];
            accYa = __builtin_amdgcn_mfma_f32_32x32x16_bf16(a1, rA1T[1], accYa, 0, 0, 0);
            accYb = __builtin_amdgcn_mfma_f32_32x32x16_bf16(b1, rA1T[1], accYb, 0, 0, 0);
        }

        // ---- P2: H^T = relu(W1 @ Y^T); Y consumed in-register
        bf16x8 yba, ybb;
        #pragma unroll
        for (int jj = 0; jj < 8; jj++) {
            yba[jj] = (half == 0 && jj < 4) ? (__bf16)accYa[jj] : (__bf16)0.f;
            ybb[jj] = (half == 0 && jj < 4) ? (__bf16)accYb[jj] : (__bf16)0.f;
        }
        #pragma unroll
        for (int tt = 0; tt < 2; tt++) {
            f32x16 acca = __builtin_amdgcn_mfma_f32_32x32x16_bf16(rW1[tt], yba, Z, 0, 0, 0);
            f32x16 accb = __builtin_amdgcn_mfma_f32_32x32x16_bf16(rW1[tt], ybb, Z, 0, 0, 0);
            #pragma unroll
            for (int g = 0; g < 4; g++) {
                bf16x4 pa, pb;
                #pragma unroll
                for (int r2 = 0; r2 < 4; r2++) {
                    pa[r2] = (__bf16)fmaxf(acca[4 * g + r2], 0.f);
                    pb[r2] = (__bf16)fmaxf(accb[4 * g + r2], 0.f);
                }
                *(bf16x4*)&sa[(tt * 4 + g) * 264 + fo + 4 * half] = pa;
                *(bf16x4*)&sb[(tt * 4 + g) * 264 + fo + 4 * half] = pb;
            }
        }

        // ---- P3: U = H @ W2  (C cols = l, rows = i)
        f32x16 accUa, accUb;
        {
            bf16x8 a0 = *(const bf16x8*)&sa[half * 264 + fo];
            bf16x8 b0 = *(const bf16x8*)&sb[half * 264 + fo];
            accUa = __builtin_amdgcn_mfma_f32_32x32x16_bf16(a0, rW2[0], Z, 0, 0, 0);
            accUb = __builtin_amdgcn_mfma_f32_32x32x16_bf16(b0, rW2[0], Z, 0, 0, 0);
            #pragma unroll
            for (int ks = 1; ks < 4; ks++) {
                bf16x8 a = *(const bf16x8*)&sa[(half + 2 * ks) * 264 + fo];
                bf16x8 b = *(const bf16x8*)&sb[(half + 2 * ks) * 264 + fo];
                accUa = __builtin_amdgcn_mfma_f32_32x32x16_bf16(a, rW2[ks], accUa, 0, 0, 0);
                accUb = __builtin_amdgcn_mfma_f32_32x32x16_bf16(b, rW2[ks], accUb, 0, 0, 0);
            }
        }
        #pragma unroll
        for (int g = 0; g < 4; g++) {
            bf16x4 pa, pb;
            #pragma unroll
            for (int r2 = 0; r2 < 4; r2++) {
                pa[r2] = (__bf16)accUa[4 * g + r2];
                pb[r2] = (__bf16)accUb[4 * g + r2];
            }
            *(bf16x4*)&sa[g * 264 + fo + 4 * half] = pa;
            *(bf16x4*)&sb[g * 264 + fo + 4 * half] = pb;
        }

        // ---- P4: V^T = U^T @ App^T  (C cols = i', rows = l)
        f32x16 accVa, accVb;
        {
            bf16x8 a0 = *(const bf16x8*)&sa[half * 264 + fo];
            bf16x8 b0 = *(const bf16x8*)&sb[half * 264 + fo];
            accVa = __builtin_amdgcn_mfma_f32_32x32x16_bf16(a0, rApp[0], Z, 0, 0, 0);
            accVb = __builtin_amdgcn_mfma_f32_32x32x16_bf16(b0, rApp[0], Z, 0, 0, 0);
            bf16x8 a1 = *(const bf16x8*)&sa[(2 + half) * 264 + fo];
            bf16x8 b1 = *(const bf16x8*)&sb[(2 + half) * 264 + fo];
            accVa = __builtin_amdgcn_mfma_f32_32x32x16_bf16(a1, rApp[1], accVa, 0, 0, 0);
            accVb = __builtin_amdgcn_mfma_f32_32x32x16_bf16(b1, rApp[1], accVb, 0, 0, 0);
        }
        #pragma unroll
        for (int g = 0; g < 4; g++) {
            bf16x4 pa, pb;
            #pragma unroll
            for (int r2 = 0; r2 < 4; r2++) {
                pa[r2] = (__bf16)accVa[4 * g + r2];
                pb[r2] = (__bf16)accVb[4 * g + r2];
            }
            *(bf16x4*)&sa[(4 + g) * 264 + fo + 4 * half] = pa;
            *(bf16x4*)&sb[(4 + g) * 264 + fo + 4 * half] = pb;
        }

        // ---- P5: HD^T = relu(W3 @ V^T + bpp)
        bf16x8 va0 = *(const bf16x8*)&sa[(4 + half) * 264 + fo];
        bf16x8 va1 = *(const bf16x8*)&sa[(6 + half) * 264 + fo];
        bf16x8 vb0 = *(const bf16x8*)&sb[(4 + half) * 264 + fo];
        bf16x8 vb1 = *(const bf16x8*)&sb[(6 + half) * 264 + fo];
        #pragma unroll
        for (int tt = 0; tt < 2; tt++) {
            f32x16 acca = __builtin_amdgcn_mfma_f32_32x32x16_bf16(rW3[tt * 2 + 0], va0, Z, 0, 0, 0);
            f32x16 accb = __builtin_amdgcn_mfma_f32_32x32x16_bf16(rW3[tt * 2 + 0], vb0, Z, 0, 0, 0);
            acca = __builtin_amdgcn_mfma_f32_32x32x16_bf16(rW3[tt * 2 + 1], va1, acca, 0, 0, 0);
            accb = __builtin_amdgcn_mfma_f32_32x32x16_bf16(rW3[tt * 2 + 1], vb1, accb, 0, 0, 0);
            #pragma unroll
            for (int g = 0; g < 4; g++) {
                bf16x4 pa, pb;
                #pragma unroll
                for (int r2 = 0; r2 < 4; r2++) {
                    const int q = g * 4 + r2;
                    const float bias = (float)rBpp[tt * 2 + (q >> 3)][q & 7];
                    pa[r2] = (__bf16)fmaxf(acca[4 * g + r2] + bias, 0.f);
                    pb[r2] = (__bf16)fmaxf(accb[4 * g + r2] + bias, 0.f);
                }
                *(bf16x4*)&sa[(tt * 4 + g) * 264 + fo + 4 * half] = pa;
                *(bf16x4*)&sb[(tt * 4 + g) * 264 + fo + 4 * half] = pb;
            }
        }

        // ---- P6: P = HD @ W4  (C cols = c, rows = i')
        f32x16 accPa, accPb;
        {
            bf16x8 a0 = *(const bf16x8*)&sa[half * 264 + fo];
            bf16x8 b0 = *(const bf16x8*)&sb[half * 264 + fo];
            accPa = __builtin_amdgcn_mfma_f32_32x32x16_bf16(a0, rW4[0], Z, 0, 0, 0);
            accPb = __builtin_amdgcn_mfma_f32_32x32x16_bf16(b0, rW4[0], Z, 0, 0, 0);
            #pragma unroll
            for (int ks = 1; ks < 4; ks++) {
                bf16x8 a = *(const bf16x8*)&sa[(half + 2 * ks) * 264 + fo];
                bf16x8 b = *(const bf16x8*)&sb[(half + 2 * ks) * 264 + fo];
                accPa = __builtin_amdgcn_mfma_f32_32x32x16_bf16(a, rW4[ks], accPa, 0, 0, 0);
                accPb = __builtin_amdgcn_mfma_f32_32x32x16_bf16(b, rW4[ks], accPb, 0, 0, 0);
            }
        }
        #pragma unroll
        for (int g = 0; g < 4; g++) {
            bf16x4 pa, pb;
            #pragma unroll
            for (int r2 = 0; r2 < 4; r2++) {
                pa[r2] = (__bf16)accPa[4 * g + r2];
                pb[r2] = (__bf16)accPb[4 * g + r2];
            }
            *(bf16x4*)&sa[g * 264 + fo + 4 * half] = pa;
            *(bf16x4*)&sb[g * 264 + fo + 4 * half] = pb;
        }

        // ---- P7: out = A4 @ P + b4, direct global stores
        f32x16 accOa, accOb;
        {
            bf16x8 a0 = *(const bf16x8*)&sa[half * 264 + fo];
            bf16x8 b0 = *(const bf16x8*)&sb[half * 264 + fo];
            accOa = __builtin_amdgcn_mfma_f32_32x32x16_bf16(rA4b[0], a0, Z, 0, 0, 0);
            accOb = __builtin_amdgcn_mfma_f32_32x32x16_bf16(rA4b[0], b0, Z, 0, 0, 0);
            bf16x8 a1 = *(const bf16x8*)&sa[(2 + half) * 264 + fo];
            bf16x8 b1 = *(const bf16x8*)&sb[(2 + half) * 264 + fo];
            accOa = __builtin_amdgcn_mfma_f32_32x32x16_bf16(rA4b[1], a1, accOa, 0, 0, 0);
            accOb = __builtin_amdgcn_mfma_f32_32x32x16_bf16(rA4b[1], b1, accOb, 0, 0, 0);
        }
        if (ln < 3) {
            const long oa = fA * NJC, ob = fB * NJC;
            #pragma unroll
            for (int r = 0; r < 16; r++) {
                const int row = (r & 3) + 8 * (r >> 2) + 4 * half;
                if (row < J) {
                    out[oa + row * 3 + ln] = accOa[r] + b4v;
                    out[ob + row * 3 + ln] = accOb[r] + b4v;
                }
            }
        }

        xa0 = nxa0; xa1 = nxa1; xb0 = nxb0; xb1 = nxb1;
    }
}

// ---------------------------------------------------------------------------
extern "C" void kernel_launch(void* const* d_in, const int* in_sizes, int n_in,
                              void* d_out, int out_size, void* d_ws, size_t ws_size,
                              hipStream_t stream)
{
    const float* x  = (const float*)d_in[0];
    const float* A1 = (const float*)d_in[1];
    const float* W1 = (const float*)d_in[2];
    const float* b1 = (const float*)d_in[3];
    const float* A2 = (const float*)d_in[4];
    const float* W2 = (const float*)d_in[5];
    const float* b2 = (const float*)d_in[6];
    const float* A3 = (const float*)d_in[7];
    const float* W3 = (const float*)d_in[8];
    const float* b3 = (const float*)d_in[9];
    const float* A4 = (const float*)d_in[10];
    const float* W4 = (const float*)d_in[11];
    const float* b4 = (const float*)d_in[12];
    float* out = (float*)d_out;
    __bf16* cw = (__bf16*)d_ws;

    const int NT = in_sizes[0] / NJC;                 // 65536
    const int nblocks = NT / (NWAVE * NFPW);          // 2048

    gcn_precompute<<<1, 256, 0, stream>>>(
        A1, W1, b1, A2, W2, b2, A3, W3, b3, A4, W4, b4, cw);
    gcn_fused<<<nblocks, NTHREADS, 0, stream>>>(x, cw, out);
}